// Round 8
// baseline (261.666 us; speedup 1.0000x reference)
//
#include <hip/hip_runtime.h>
#include <hip/hip_bf16.h>
#include <cfloat>
#include <climits>

typedef short  short8v __attribute__((ext_vector_type(8)));
typedef float  f32x4   __attribute__((ext_vector_type(4)));

#define NQ    128   // queries (fixed by problem)
#define SR    16    // rows per strip (one MFMA A-tile)
#define SPC   8     // strips per chunk
#define RPC   (SR * SPC)     // 128 rows per chunk
#define EMIT  3     // candidates per query per chunk
#define GBLK  1024  // persistent grid: 4096 waves = 4/SIMD, one generation
#define CSTR  2048  // chunk stride per wave (GBLK*2)
#define K2    6     // per-thread top-k in phase 2 stream scan
#define KSEL  24    // approx top-K kept for exact rescore
#define KK    10    // final k

__device__ __forceinline__ bool pair_less(float d1, int i1, float d2, int i2) {
    return (d1 < d2) || (d1 == d2 && i1 < i2);
}

__device__ __forceinline__ unsigned pk2(float a, float b) {
    union { __hip_bfloat162 h; unsigned u; } cv;
    cv.h = __float22bfloat162_rn(make_float2(a, b));
    return cv.u;
}
__device__ __forceinline__ short8v pack8(float4 a, float4 b) {
    union { unsigned u[4]; short8v s; } cv;
    cv.u[0] = pk2(a.x, a.y); cv.u[1] = pk2(a.z, a.w);
    cv.u[2] = pk2(b.x, b.y); cv.u[3] = pk2(b.z, b.w);
    return cv.s;
}

// top-2 insert, key-only strict < (stream ascending-idx => stable ties)
__device__ __forceinline__ void ins2(float (&d)[2], int (&ix)[2], float key, int idx) {
    if (!(key < d[1])) return;
    d[1] = key; ix[1] = idx;
    bool sw = d[1] < d[0];
    float a = d[0], b = d[1]; int ai = ix[0], bi2 = ix[1];
    d[0] = sw ? b : a; ix[0] = sw ? bi2 : ai;
    d[1] = sw ? a : b; ix[1] = sw ? ai : bi2;
}

// capacity-3 (key,idx)-ordered insert for the cross-lane merge
__device__ __forceinline__ void ins3p(float (&d)[3], int (&ix)[3], float key, int idx) {
    if (!pair_less(key, idx, d[2], ix[2])) return;
    d[2] = key; ix[2] = idx;
#pragma unroll
    for (int j = 2; j > 0; --j) {
        float a = d[j - 1], b = d[j]; int ai = ix[j - 1], bi2 = ix[j];
        bool sw = pair_less(b, bi2, a, ai);
        d[j - 1] = sw ? b : a; ix[j - 1] = sw ? bi2 : ai;
        d[j]     = sw ? a : b; ix[j]     = sw ? ai : bi2;
    }
}

__device__ __forceinline__ void ins6(float (&d)[K2], int (&ix)[K2], float key, int idx) {
    if (!pair_less(key, idx, d[K2 - 1], ix[K2 - 1])) return;
    d[K2 - 1] = key; ix[K2 - 1] = idx;
#pragma unroll
    for (int j = K2 - 1; j > 0; --j) {
        float a = d[j - 1], b = d[j]; int ai = ix[j - 1], bi2 = ix[j];
        bool sw = pair_less(b, bi2, a, ai);
        d[j - 1] = sw ? b : a; ix[j - 1] = sw ? bi2 : ai;
        d[j]     = sw ? a : b; ix[j]     = sw ? ai : bi2;
    }
}

__device__ __forceinline__ void argmin64(float& k, int& i, int& l) {
#pragma unroll
    for (int off = 32; off; off >>= 1) {
        float ok = __shfl_xor(k, off);
        int   oi = __shfl_xor(i, off);
        int   ol = __shfl_xor(l, off);
        bool take = pair_less(ok, oi, k, i) || (ok == k && oi == i && ol < l);
        k = take ? ok : k; i = take ? oi : i; l = take ? ol : l;
    }
}

// ---------------- Phase 1: persistent waves, no LDS, no barriers ------------
// 1024 blocks x 4 waves = full 4/SIMD generation. Wave wv of block blk:
// queries [qbase, qbase+64) (qbase=(wv>>1)*64), chunk stream
// c0 = blk*2+(wv&1), c0+2048, ... < nchunks. bfrag loaded ONCE per wave.
// Double-buffered register prefetch runs continuously across chunk bounds.
// psq enters the accumulator via the matrix unit (A2/B2 trick) — zero DS ops.
__global__ __launch_bounds__(256, 4) void phase1(
        const float* __restrict__ x, const float* __restrict__ pool_x,
        float2* __restrict__ cand, int N, int nchunks) {
    const int t = threadIdx.x, wv = t >> 6, lane = t & 63;
    const int c = lane & 15, g = lane >> 4;
    const int qbase = (wv >> 1) * 64;
    const int c0 = blockIdx.x * 2 + (wv & 1);

    // B fragments: 4 tiles x 16 queries; B'[k][q]=bf16(-2 x[q][k]). 32 VGPRs.
    short8v bfrag[4][2];
#pragma unroll
    for (int tt = 0; tt < 4; ++tt)
#pragma unroll
        for (int ks = 0; ks < 2; ++ks) {
            const float* xp = x + (qbase + tt * 16 + c) * 64 + ks * 32 + g * 8;
            float4 u0 = *(const float4*)xp;
            float4 u1 = *(const float4*)(xp + 4);
            u0.x *= -2.f; u0.y *= -2.f; u0.z *= -2.f; u0.w *= -2.f;
            u1.x *= -2.f; u1.y *= -2.f; u1.z *= -2.f; u1.w *= -2.f;
            bfrag[tt][ks] = pack8(u0, u1);
        }

    // B2: 1.0 at k in {0,8,16,24} -> every lane holds {1,0,...}
    short8v b2 = {0, 0, 0, 0, 0, 0, 0, 0};
    b2[0] = (short)0x3F80;

    float4 buf[2][4];
    auto LOAD = [&](long rowbase, int b) {        // rowbase = strip's first row
        long r = rowbase + c;
        if (r > (long)N - 1) r = (long)N - 1;
        const float* pr = pool_x + r * 64 + g * 8;
        buf[b][0] = *(const float4*)pr;
        buf[b][1] = *(const float4*)(pr + 4);
        buf[b][2] = *(const float4*)(pr + 32);
        buf[b][3] = *(const float4*)(pr + 36);
    };

    if (c0 < nchunks) LOAD((long)c0 * RPC, 0);

#pragma unroll 1
    for (int cc = c0; cc < nchunks; cc += CSTR) {
        const long brow = (long)cc * RPC;

        float bd[4][2]; int bi[4][2];
#pragma unroll
        for (int tt = 0; tt < 4; ++tt) {
            bd[tt][0] = FLT_MAX; bd[tt][1] = FLT_MAX;
            bi[tt][0] = INT_MAX; bi[tt][1] = INT_MAX;
        }

#pragma unroll
        for (int s = 0; s < SPC; ++s) {
            const int b = s & 1;
            // prefetch next strip in the stream (same chunk, or next chunk's
            // strip 0) into the other buffer BEFORE using buf[b].
            if (s + 1 < SPC) {
                LOAD(brow + (long)(s + 1) * SR, b ^ 1);
            } else if (cc + CSTR < nchunks) {
                LOAD((long)(cc + CSTR) * RPC, b ^ 1);
            }
            float4 f0 = buf[b][0], f1 = buf[b][1], f2 = buf[b][2], f3 = buf[b][3];

            // partial psq over this lane's 16 dims -> bf16 into A2 slot 0
            float ps = f0.x * f0.x + f0.y * f0.y + f0.z * f0.z + f0.w * f0.w
                     + f1.x * f1.x + f1.y * f1.y + f1.z * f1.z + f1.w * f1.w
                     + f2.x * f2.x + f2.y * f2.y + f2.z * f2.z + f2.w * f2.w
                     + f3.x * f3.x + f3.y * f3.y + f3.z * f3.z + f3.w * f3.w;
            if (brow + (long)s * SR + c >= N) ps = __builtin_inff();

            short8v a2 = {0, 0, 0, 0, 0, 0, 0, 0};
            union { unsigned u; short s2[2]; } pv; pv.u = pk2(ps, 0.f);
            a2[0] = pv.s2[0];

            short8v a0 = pack8(f0, f1);    // k = 0..31
            short8v a1 = pack8(f2, f3);    // k = 32..63

            f32x4 zc = {0.f, 0.f, 0.f, 0.f};
            f32x4 pacc = __builtin_amdgcn_mfma_f32_16x16x32_bf16(a2, b2, zc, 0, 0, 0);

            const int rowb = (int)brow + s * SR + g * 4;
#pragma unroll
            for (int tt = 0; tt < 4; ++tt) {
                f32x4 acc = __builtin_amdgcn_mfma_f32_16x16x32_bf16(a0, bfrag[tt][0], pacc, 0, 0, 0);
                acc = __builtin_amdgcn_mfma_f32_16x16x32_bf16(a1, bfrag[tt][1], acc, 0, 0, 0);
                float mn = fminf(fminf(acc[0], acc[1]), fminf(acc[2], acc[3]));
                if (mn < bd[tt][1]) {
#pragma unroll
                    for (int r = 0; r < 4; ++r) ins2(bd[tt], bi[tt], acc[r], rowb + r);
                }
            }
        }

        // per-chunk emit: butterfly over the 4 g-lanes (capacity 3), g<3 emit.
#pragma unroll
        for (int tt = 0; tt < 4; ++tt) {
            float md[3] = {bd[tt][0], bd[tt][1], FLT_MAX};
            int   mi[3] = {bi[tt][0], bi[tt][1], INT_MAX};
#pragma unroll
            for (int m = 16; m <= 32; m <<= 1) {
                float od[3]; int oi[3];
#pragma unroll
                for (int j = 0; j < 3; ++j) { od[j] = __shfl_xor(md[j], m); oi[j] = __shfl_xor(mi[j], m); }
#pragma unroll
                for (int j = 0; j < 3; ++j) ins3p(md, mi, od[j], oi[j]);
            }
            if (g < 3) {
                int q = qbase + tt * 16 + c;
                cand[((size_t)cc * NQ + q) * EMIT + g] =
                    make_float2(md[g], __int_as_float(mi[g]));
            }
        }
    }
}

// ---------------- Phase 2: merge -> approx top-24 -> exact rescore -> top-10
__global__ __launch_bounds__(256) void phase2(
        const float2* __restrict__ cand, const float* __restrict__ x,
        const float* __restrict__ pool_x, const float* __restrict__ pool_y,
        float* __restrict__ out, int nchunks, int N) {
    __shared__ float xs[64];
    __shared__ float wd[4 * KSEL]; __shared__ int wi[4 * KSEL];
    __shared__ float sd[KSEL];     __shared__ int si[KSEL];
    __shared__ float rk[64];
    __shared__ int   fi[KK];

    const int t = threadIdx.x, wave = t >> 6, lane = t & 63;
    const int q = blockIdx.x;
    if (t < 64) xs[t] = x[q * 64 + t];

    float d[K2]; int ix[K2];
#pragma unroll
    for (int j = 0; j < K2; ++j) { d[j] = FLT_MAX; ix[j] = INT_MAX; }

    for (int ch = t; ch < nchunks; ch += 256) {
        const float2* e = cand + ((size_t)ch * NQ + q) * EMIT;
#pragma unroll
        for (int g2 = 0; g2 < EMIT; ++g2) {
            float2 v = e[g2];
            ins6(d, ix, v.x, __float_as_int(v.y));
        }
    }

    // per-wave extraction of its top-KSEL
    for (int r = 0; r < KSEL; ++r) {
        float mk = d[0]; int mi = ix[0]; int ml = lane;
        argmin64(mk, mi, ml);
        if (lane == ml) {
#pragma unroll
            for (int j = 0; j < K2 - 1; ++j) { d[j] = d[j + 1]; ix[j] = ix[j + 1]; }
            d[K2 - 1] = FLT_MAX; ix[K2 - 1] = INT_MAX;
        }
        if (lane == 0) { wd[wave * KSEL + r] = mk; wi[wave * KSEL + r] = mi; }
    }
    __syncthreads();

    // wave 0 merges 4xKSEL=96 -> global approx top-KSEL
    if (wave == 0) {
        float e0 = wd[lane]; int e0i = wi[lane];
        float e1 = (lane + 64 < 4 * KSEL) ? wd[lane + 64] : FLT_MAX;
        int  e1i = (lane + 64 < 4 * KSEL) ? wi[lane + 64] : INT_MAX;
        if (pair_less(e1, e1i, e0, e0i)) {
            float tf = e0; e0 = e1; e1 = tf;
            int   ti = e0i; e0i = e1i; e1i = ti;
        }
        for (int r = 0; r < KSEL; ++r) {
            float mk = e0; int mi = e0i; int ml = lane;
            argmin64(mk, mi, ml);
            if (lane == ml) { e0 = e1; e0i = e1i; e1 = FLT_MAX; e1i = INT_MAX; }
            if (lane == 0) { sd[r] = mk; si[r] = mi; }
        }
    }
    __syncthreads();

    // exact fp32 rescore of the KSEL survivors
    if (t < 64) {
        float key = FLT_MAX;
        if (t < KSEL) {
            int idx = si[t];
            if (idx >= 0 && idx < N) {
                const float4* pr = (const float4*)(pool_x + (size_t)idx * 64);
                const float4* xv = (const float4*)xs;
                float psq = 0.f, dot = 0.f;
#pragma unroll
                for (int k4 = 0; k4 < 16; ++k4) {
                    float4 p = pr[k4]; float4 xw = xv[k4];
                    psq += p.x * p.x + p.y * p.y + p.z * p.z + p.w * p.w;
                    dot += p.x * xw.x + p.y * xw.y + p.z * xw.z + p.w * xw.w;
                }
                key = psq - 2.0f * dot;
            }
        }
        rk[t] = key;
    }
    __syncthreads();

    // exact top-10 by (key, idx)
    if (wave == 0) {
        float mykey = rk[lane];
        int myidx = (lane < KSEL) ? si[lane] : INT_MAX;
        for (int r = 0; r < KK; ++r) {
            float mk = mykey; int mi = myidx; int ml = lane;
            argmin64(mk, mi, ml);
            if (lane == ml) { mykey = FLT_MAX; myidx = INT_MAX; }
            if (lane == 0) fi[r] = mi;
        }
    }
    __syncthreads();

    // gather output rows: [q][j][0:64]=pool_x[idx], [q][j][64]=pool_y[idx]
    for (int e = t; e < KK * 65; e += 256) {
        int j = e / 65, cdim = e - j * 65;
        int idx = fi[j];
        out[(size_t)q * (KK * 65) + e] = (cdim < 64) ? pool_x[(size_t)idx * 64 + cdim]
                                                     : pool_y[idx];
    }
}

extern "C" void kernel_launch(void* const* d_in, const int* in_sizes, int n_in,
                              void* d_out, int out_size, void* d_ws, size_t ws_size,
                              hipStream_t stream) {
    const float* x      = (const float*)d_in[0];
    const float* pool_x = (const float*)d_in[1];
    const float* pool_y = (const float*)d_in[2];
    const int N = in_sizes[1] / 64;

    const int nchunks = (N + RPC - 1) / RPC;   // 3907 at N=500000

    float2* cand = (float2*)d_ws;   // [nchunks][NQ][EMIT] {key, idx-bits}

    hipLaunchKernelGGL(phase1, dim3(GBLK), dim3(256), 0, stream,
                       x, pool_x, cand, N, nchunks);
    hipLaunchKernelGGL(phase2, dim3(NQ), dim3(256), 0, stream,
                       cand, x, pool_x, pool_y, (float*)d_out, nchunks, N);
}